// Round 16
// baseline (141.818 us; speedup 1.0000x reference)
//
#include <hip/hip_runtime.h>
#include <cmath>

typedef __bf16 bf16;
typedef __bf16 bf16x8 __attribute__((ext_vector_type(8)));
typedef float f32x4 __attribute__((ext_vector_type(4)));

#define SBAR() __builtin_amdgcn_sched_barrier(0)

// B=16, C_IN=256, H=W=64, C_OUT=256, 3x3, stride 1, pad 1, CURV=1

__device__ inline void gload16(const void* g, void* l) {
    __builtin_amdgcn_global_load_lds(
        (const __attribute__((address_space(1))) unsigned int*)g,
        (__attribute__((address_space(3))) unsigned int*)l, 16, 0, 0);
}

// ---------------------------------------------------------------------------
// Weight transform: z[k=c*9+tap][co] -> zt5[s=cc*9+tap][gran4][co256][8ch]
// (r11 layout: LDS staging is a linear 16 KB copy; frag read consecutive-co).
__global__ void k_prep_zt(const float* __restrict__ z, bf16* __restrict__ zt5) {
    int s = blockIdx.x;                // 72 = cc*9 + tap, cc in 0..7 (32ch)
    int cc = s / 9, tap = s % 9;
    int co = threadIdx.x;
#pragma unroll
    for (int g = 0; g < 4; ++g) {
        bf16x8 pk;
#pragma unroll
        for (int e = 0; e < 8; ++e) {
            int c = cc * 32 + g * 8 + e;
            pk[e] = (bf16)z[(size_t)(c * 9 + tap) * 256 + co];
        }
        *(bf16x8*)(zt5 + ((size_t)(s * 4 + g) * 256 + co) * 8) = pk;
    }
}

// Column constants
__global__ void k_prep_cols(const float* __restrict__ z, const float* __restrict__ r,
                            float* __restrict__ zn, float* __restrict__ ch,
                            float* __restrict__ sh) {
    __shared__ float red[256];
    int co = blockIdx.x, t = threadIdx.x;
    float s = 0.f;
    for (int i = 0; i < 9; ++i) {
        float v = z[(size_t)(i * 256 + t) * 256 + co];
        s += v * v;
    }
    red[t] = s;
    __syncthreads();
    for (int off = 128; off >= 1; off >>= 1) {
        if (t < off) red[t] += red[t + off];
        __syncthreads();
    }
    if (t == 0) {
        zn[co] = fmaxf(sqrtf(red[0]), 1e-15f);
        float tc = 2.f * r[co];
        ch[co] = coshf(tc);
        sh[co] = sinhf(tc);
    }
}

// ---------------------------------------------------------------------------
// logmap0 * beta-ratio, transpose -> vt[B,HW,C] bf16, per-pixel sq (fp32).
__global__ void k_logmap(const float* __restrict__ x, unsigned int* __restrict__ vt_u,
                         float* __restrict__ sq, float Rbeta) {
    __shared__ float tile[256][33];
    __shared__ float red[8][32];
    __shared__ float afac[32];
    int tid = threadIdx.x;
    int blk = blockIdx.x;
    int b = blk >> 7;
    int pix0 = (blk & 127) << 5;

    for (int it = 0; it < 32; ++it) {
        int c = it * 8 + (tid >> 5);
        int p = tid & 31;
        tile[c][p] = x[((size_t)b * 256 + c) * 4096 + pix0 + p];
    }
    __syncthreads();

    {
        int part = tid >> 5, p = tid & 31;
        float s = 0.f;
        for (int i = 0; i < 32; ++i) {
            float v = tile[part * 32 + i][p];
            s += v * v;
        }
        red[part][p] = s;
    }
    __syncthreads();
    if (tid < 32) {
        float n2 = 0.f;
        for (int i = 0; i < 8; ++i) n2 += red[i][tid];
        float n = sqrtf(n2);
        float nc = fmaxf(n, 1e-15f);
        float a = atanhf(fminf(nc, 0.9999999f)) / nc * Rbeta;
        afac[tid] = a;
        sq[(size_t)b * 4096 + pix0 + tid] = a * a * n2;
    }
    __syncthreads();

    for (int it = 0; it < 16; ++it) {
        int idx = it * 256 + tid;
        int p = idx >> 7;
        int cp = idx & 127;
        float a = afac[p];
        float v0 = a * tile[2 * cp][p];
        float v1 = a * tile[2 * cp + 1][p];
        union { bf16 h[2]; unsigned int u; } pk;
        pk.h[0] = (bf16)v0;
        pk.h[1] = (bf16)v1;
        vt_u[((size_t)b * 4096 + pix0 + p) * 128 + cp] = pk.u;
    }
}

// ---------------------------------------------------------------------------
// Fused implicit-GEMM conv + hyperbolic FC epilogue — PIPELINED schedule.
// r9-r15 lesson: every {stage->wait->barrier->compute} skeleton variant hits
// the 2-phase ceiling (~98-122us = 630-790 TF; catalog m230/m233). This is
// the T3+T4 port: per stage {issue gB(s+2)[,gA(cc+1)]} -> counted vmcnt ->
// 1 barrier -> ds_read frags(s+1) into regs -> MFMA(frags(s)) with compiler
// lgkmcnt interleave. B triple-buffered (static parities, no trailing
// barrier), A double-buffered per cc. 256-reg budget (waves_per_eu(2,2))
// gives the frag double-buffer headroom the 128-cap rounds lacked.
__global__ void
__attribute__((amdgpu_flat_work_group_size(512, 512)))
__attribute__((amdgpu_waves_per_eu(2, 2)))
k_hconv(const bf16* __restrict__ vt, const bf16* __restrict__ zt5,
        const float* __restrict__ sq,
        const float* __restrict__ znp, const float* __restrict__ chp,
        const float* __restrict__ shp, float* __restrict__ out) {
    __shared__ __align__(1024) char Ab[2][16896];    // 16 units x 1056 B each
    __shared__ __align__(1024) char Bb3[3][16448];   // 4 gran x 4112 B each
    __shared__ float s_lds[128], lam_lds[128];
    __shared__ float red[128][4];

    int tid = threadIdx.x;
    int bid = blockIdx.x;
    int bh = ((bid & 7) << 6) | (bid >> 3);   // XCD-bijective: 512 = 8 x 64
    int b = bh >> 5, h0 = (bh & 31) << 1;

    // zero halo slots (0 and 65) of both A buffers, once
    if (tid < 64) {
        int buf = tid >> 5, rem = tid & 31;
        int u = rem >> 1, side = rem & 1;
        *(f32x4*)(Ab[buf] + u * 1056 + side * 1040) = (f32x4){0.f, 0.f, 0.f, 0.f};
    }

    if (tid >= 128 && tid < 256) {
        int t = tid - 128;
        int h = h0 + (t >> 6), w = t & 63;
        const float* sb = sq + ((size_t)b << 12);
        float q = 0.f;
#pragma unroll
        for (int dh = -1; dh <= 1; ++dh) {
            int hhh = h + dh;
            if ((unsigned)hhh >= 64u) continue;
#pragma unroll
            for (int dw = -1; dw <= 1; ++dw) {
                int ww = w + dw;
                if ((unsigned)ww >= 64u) continue;
                q += sb[hhh * 64 + ww];
            }
        }
        float ncl = fmaxf(sqrtf(q), 1e-15f);
        float p = __expf(2.f * ncl);
        float tt = (p - 1.f) / (p + 1.f);        // tanh(ncl)
        s_lds[t] = tt / ncl;                     // expmap scale
        lam_lds[t] = 2.f / (1.f - tt * tt);
    }

    int wave = tid >> 6, lane = tid & 63;
    int wn = wave & 3, wm = wave >> 2;    // wm row 0..1, wn co-quarter 0..3
    int lrow = lane & 15, lk = lane >> 4;

    f32x4 acc[4][4];
#pragma unroll
    for (int m = 0; m < 4; ++m)
#pragma unroll
        for (int n = 0; n < 4; ++n) acc[m][n] = (f32x4){0.f, 0.f, 0.f, 0.f};

    const bf16* vb = vt + (((size_t)b) << 12) * 256;

    // stage A chunk ccn into raw buffer dst: 16 units (r4 x g4); 2/wave
    auto stageA = [&](char* dst, int ccn) {
#pragma unroll
        for (int it = 0; it < 2; ++it) {
            int u = wave * 2 + it;
            int r = u >> 2, g = u & 3;
            int hr = h0 - 1 + r;
            hr = hr < 0 ? 0 : (hr > 63 ? 63 : hr);   // clamped rows never read
            const bf16* gp = vb + ((size_t)(hr * 64 + lane)) * 256 + ccn * 32 + g * 8;
            gload16(gp, dst + u * 1056 + 16);
        }
    };
    // stage B stage s into raw buffer dst: linear 16 KB; 2/wave
    auto stageB = [&](char* dst, int s) {
        const char* src = (const char*)zt5 + (size_t)s * 16384;
#pragma unroll
        for (int it = 0; it < 2; ++it) {
            int u = wave * 2 + it;
            gload16(src + u * 1024 + lane * 16,
                    dst + (u >> 2) * 4112 + (u & 3) * 1024);
        }
    };

    // prologue: B(0)->buf0, B(1)->buf1, A(0)->Ab0; drain; read frags(0)
    stageB((char*)Bb3[0], 0);
    stageB((char*)Bb3[1], 1);
    stageA((char*)Ab[0], 0);
    __syncthreads();                      // drains vmcnt; s_lds visible
    SBAR();

    const char* Ac = Ab[0] + lk * 1056 + lrow * 16;   // per-lane frag bases
    const char* An_ = Ab[1] + lk * 1056 + lrow * 16;
    const int bOff = lk * 4112 + wn * 1024 + lrow * 16;

    bf16x8 afA[4], afB[4], bfA[4], bfB[4];
#pragma unroll
    for (int m = 0; m < 4; ++m)           // frags for s=0: tap0 dh=-1,dw=-1
        afA[m] = *(const bf16x8*)(Ac + wm * 4224 + m * 256);
#pragma unroll
    for (int n = 0; n < 4; ++n)
        bfA[n] = *(const bf16x8*)((const char*)Bb3[0] + bOff + n * 256);

// AFC/BFC: frags for stage (CCV,TAP); AFN/BFN: filled with frags(s+1).
// ARD: per-lane A frag base for CCV; ARN: for CCV+1. ASTG: raw target buffer
// for stageA. DOA: issue gA this stage (TAP==0 only). LAST: CCV==7.
#define STAGE(CCV, TAP, AFC, BFC, AFN, BFN, ARD, ARN, ASTG, DOA, LAST)       \
    {                                                                        \
        const int s_ = (CCV) * 9 + (TAP);                                    \
        if (s_ + 2 < 72) stageB((char*)Bb3[((TAP) + 2) % 3], s_ + 2);        \
        if ((TAP) == 0 && (DOA)) stageA((char*)(ASTG), (CCV) + 1);           \
        SBAR();                                                              \
        if ((TAP) < 2) {                                                     \
            if (LAST) { asm volatile("s_waitcnt vmcnt(2)" ::: "memory"); }   \
            else      { asm volatile("s_waitcnt vmcnt(4)" ::: "memory"); }   \
        } else if ((TAP) >= 7) {                                             \
            if (LAST) { asm volatile("s_waitcnt vmcnt(0)" ::: "memory"); }   \
            else      { asm volatile("s_waitcnt vmcnt(2)" ::: "memory"); }   \
        } else {                                                             \
            asm volatile("s_waitcnt vmcnt(2)" ::: "memory");                 \
        }                                                                    \
        SBAR();                                                              \
        asm volatile("s_barrier" ::: "memory");                              \
        SBAR();                                                              \
        {   /* ds_read frags(s+1) under MFMA(s) */                           \
            const int tn = ((TAP) == 8) ? 0 : (TAP) + 1;                     \
            const int dhn = tn / 3 - 1, dwn = tn % 3 - 1;                    \
            const char* An2 = (((TAP) == 8) ? (ARN) : (ARD)) +               \
                              (wm + dhn + 1) * 4224 + (dwn + 1) * 16;        \
            AFN[0] = *(const bf16x8*)(An2);                                  \
            AFN[1] = *(const bf16x8*)(An2 + 256);                            \
            AFN[2] = *(const bf16x8*)(An2 + 512);                            \
            AFN[3] = *(const bf16x8*)(An2 + 768);                            \
            const char* Bn2 = (const char*)Bb3[((TAP) + 1) % 3] + bOff;      \
            BFN[0] = *(const bf16x8*)(Bn2);                                  \
            BFN[1] = *(const bf16x8*)(Bn2 + 256);                            \
            BFN[2] = *(const bf16x8*)(Bn2 + 512);                            \
            BFN[3] = *(const bf16x8*)(Bn2 + 768);                            \
        }                                                                    \
        {                                                                    \
            const int dh_ = (TAP) / 3 - 1;                                   \
            int hh_ = h0 + wm + dh_;                                         \
            if ((unsigned)hh_ < 64u) {                                       \
                __builtin_amdgcn_s_setprio(1);                               \
                acc[0][0] = __builtin_amdgcn_mfma_f32_16x16x32_bf16(AFC[0], BFC[0], acc[0][0], 0, 0, 0); \
                acc[1][0] = __builtin_amdgcn_mfma_f32_16x16x32_bf16(AFC[1], BFC[0], acc[1][0], 0, 0, 0); \
                acc[2][0] = __builtin_amdgcn_mfma_f32_16x16x32_bf16(AFC[2], BFC[0], acc[2][0], 0, 0, 0); \
                acc[3][0] = __builtin_amdgcn_mfma_f32_16x16x32_bf16(AFC[3], BFC[0], acc[3][0], 0, 0, 0); \
                acc[0][1] = __builtin_amdgcn_mfma_f32_16x16x32_bf16(AFC[0], BFC[1], acc[0][1], 0, 0, 0); \
                acc[1][1] = __builtin_amdgcn_mfma_f32_16x16x32_bf16(AFC[1], BFC[1], acc[1][1], 0, 0, 0); \
                acc[2][1] = __builtin_amdgcn_mfma_f32_16x16x32_bf16(AFC[2], BFC[1], acc[2][1], 0, 0, 0); \
                acc[3][1] = __builtin_amdgcn_mfma_f32_16x16x32_bf16(AFC[3], BFC[1], acc[3][1], 0, 0, 0); \
                acc[0][2] = __builtin_amdgcn_mfma_f32_16x16x32_bf16(AFC[0], BFC[2], acc[0][2], 0, 0, 0); \
                acc[1][2] = __builtin_amdgcn_mfma_f32_16x16x32_bf16(AFC[1], BFC[2], acc[1][2], 0, 0, 0); \
                acc[2][2] = __builtin_amdgcn_mfma_f32_16x16x32_bf16(AFC[2], BFC[2], acc[2][2], 0, 0, 0); \
                acc[3][2] = __builtin_amdgcn_mfma_f32_16x16x32_bf16(AFC[3], BFC[2], acc[3][2], 0, 0, 0); \
                acc[0][3] = __builtin_amdgcn_mfma_f32_16x16x32_bf16(AFC[0], BFC[3], acc[0][3], 0, 0, 0); \
                acc[1][3] = __builtin_amdgcn_mfma_f32_16x16x32_bf16(AFC[1], BFC[3], acc[1][3], 0, 0, 0); \
                acc[2][3] = __builtin_amdgcn_mfma_f32_16x16x32_bf16(AFC[2], BFC[3], acc[2][3], 0, 0, 0); \
                acc[3][3] = __builtin_amdgcn_mfma_f32_16x16x32_bf16(AFC[3], BFC[3], acc[3][3], 0, 0, 0); \
                __builtin_amdgcn_s_setprio(0);                               \
            }                                                                \
        }                                                                    \
    }

#pragma unroll 1
    for (int cc2 = 0; cc2 < 4; ++cc2) {
        const int c0 = 2 * cc2, c1 = c0 + 1;
        const bool doA1 = (cc2 < 3);       // c1's gA target exists (cc+1<8)
        const bool last1 = (cc2 == 3);     // c1 == 7
        // c0: A frags in Ab[parity 0] (Ac), gA -> Ab[1]
        STAGE(c0, 0, afA, bfA, afB, bfB, Ac, An_, Ab[1], true,  false)
        STAGE(c0, 1, afB, bfB, afA, bfA, Ac, An_, Ab[1], false, false)
        STAGE(c0, 2, afA, bfA, afB, bfB, Ac, An_, Ab[1], false, false)
        STAGE(c0, 3, afB, bfB, afA, bfA, Ac, An_, Ab[1], false, false)
        STAGE(c0, 4, afA, bfA, afB, bfB, Ac, An_, Ab[1], false, false)
        STAGE(c0, 5, afB, bfB, afA, bfA, Ac, An_, Ab[1], false, false)
        STAGE(c0, 6, afA, bfA, afB, bfB, Ac, An_, Ab[1], false, false)
        STAGE(c0, 7, afB, bfB, afA, bfA, Ac, An_, Ab[1], false, false)
        STAGE(c0, 8, afA, bfA, afB, bfB, Ac, An_, Ab[1], false, false)
        // c1: A frags in Ab[1] (An_), gA -> Ab[0]
        STAGE(c1, 0, afB, bfB, afA, bfA, An_, Ac, Ab[0], doA1, last1)
        STAGE(c1, 1, afA, bfA, afB, bfB, An_, Ac, Ab[0], false, last1)
        STAGE(c1, 2, afB, bfB, afA, bfA, An_, Ac, Ab[0], false, last1)
        STAGE(c1, 3, afA, bfA, afB, bfB, An_, Ac, Ab[0], false, last1)
        STAGE(c1, 4, afB, bfB, afA, bfA, An_, Ac, Ab[0], false, last1)
        STAGE(c1, 5, afA, bfA, afB, bfB, An_, Ac, Ab[0], false, last1)
        STAGE(c1, 6, afB, bfB, afA, bfA, An_, Ac, Ab[0], false, last1)
        STAGE(c1, 7, afA, bfA, afB, bfB, An_, Ac, Ab[0], false, last1)
        STAGE(c1, 8, afB, bfB, afA, bfA, An_, Ac, Ab[0], false, last1)
    }
#undef STAGE

    // ---------------- epilogue (fast transcendental forms) ----------------
    float cz[4], sh4[4], tz[4];
#pragma unroll
    for (int n = 0; n < 4; ++n) {
        int co = wn * 64 + n * 16 + lrow;
        float zn = znp[co];
        cz[n] = chp[co] / zn;
        sh4[n] = shp[co];
        tz[n] = 2.f * zn;
    }

#pragma unroll
    for (int m = 0; m < 4; ++m) {
#pragma unroll
        for (int r = 0; r < 4; ++r) {
            int wp = wm * 64 + m * 16 + 4 * lk + r;   // block-local px slot
            float s = s_lds[wp], lam = lam_lds[wp];
            float lm1 = lam - 1.f;
            float psum = 0.f;
#pragma unroll
            for (int n = 0; n < 4; ++n) {
                float xz = s * acc[m][n][r];
                float inner = lam * xz * cz[n] - lm1 * sh4[n];
                float as = __logf(inner + sqrtf(inner * inner + 1.f)); // asinh
                float p = __expf(tz[n] * as);
                float w = 0.5f * (p - __builtin_amdgcn_rcpf(p));       // sinh
                acc[m][n][r] = w;
                psum += w * w;
            }
            psum += __shfl_xor(psum, 1);
            psum += __shfl_xor(psum, 2);
            psum += __shfl_xor(psum, 4);
            psum += __shfl_xor(psum, 8);
            if (lrow == 0) red[wp][wn] = psum;
        }
    }
    __syncthreads();

    float dinv[4][4];
#pragma unroll
    for (int m = 0; m < 4; ++m)
#pragma unroll
        for (int r = 0; r < 4; ++r) {
            int wp = wm * 64 + m * 16 + 4 * lk + r;
            float tot = (red[wp][0] + red[wp][1]) + (red[wp][2] + red[wp][3]);
            dinv[m][r] = __builtin_amdgcn_rcpf(1.f + sqrtf(1.f + tot));
        }

    float* ob = out + (size_t)b * 256 * 4096 + (h0 + wm) * 64;
#pragma unroll
    for (int m = 0; m < 4; ++m) {
#pragma unroll
        for (int n = 0; n < 4; ++n) {
            int co = wn * 64 + n * 16 + lrow;
            f32x4 o;
#pragma unroll
            for (int r = 0; r < 4; ++r) o[r] = acc[m][n][r] * dinv[m][r];
            *(f32x4*)(ob + (size_t)co * 4096 + m * 16 + 4 * lk) = o;
        }
    }
}

// ---------------------------------------------------------------------------
extern "C" void kernel_launch(void* const* d_in, const int* in_sizes, int n_in,
                              void* d_out, int out_size, void* d_ws, size_t ws_size,
                              hipStream_t stream) {
    const float* x = (const float*)d_in[0];   // [16,256,64,64]
    const float* z = (const float*)d_in[1];   // [2304,256]
    const float* r = (const float*)d_in[2];   // [256]
    float* out = (float*)d_out;               // [16,256,64,64]

    char* ws = (char*)d_ws;
    bf16* vt = (bf16*)ws;                         // 33,554,432 B (px-major)
    float* sq = (float*)(ws + 33554432);
    bf16* zt5 = (bf16*)(ws + 34078720);           // 72*16KB = 1,179,648 B
    float* zn = (float*)(ws + 35258368);
    float* ch = (float*)(ws + 35259392);
    float* sh = (float*)(ws + 35260416);
    if (ws_size < 35261440) return;

    double bni = lgamma(128.0) + lgamma(0.5) - lgamma(128.5);
    double bn = lgamma(1152.0) + lgamma(0.5) - lgamma(1152.5);
    float Rbeta = (float)exp(bn - bni);

    k_prep_zt<<<72, 256, 0, stream>>>(z, zt5);
    k_prep_cols<<<256, 256, 0, stream>>>(z, r, zn, ch, sh);
    k_logmap<<<2048, 256, 0, stream>>>(x, (unsigned int*)vt, sq, Rbeta);
    k_hconv<<<512, 512, 0, stream>>>(vt, zt5, sq, zn, ch, sh, out);
}

// Round 17
// 124.898 us; speedup vs baseline: 1.1355x; 1.1355x over previous
//
#include <hip/hip_runtime.h>
#include <cmath>

typedef __bf16 bf16;
typedef __bf16 bf16x8 __attribute__((ext_vector_type(8)));
typedef float f32x4 __attribute__((ext_vector_type(4)));

#define SBAR() __builtin_amdgcn_sched_barrier(0)

// B=16, C_IN=256, H=W=64, C_OUT=256, 3x3, stride 1, pad 1, CURV=1

__device__ inline void gload16(const void* g, void* l) {
    __builtin_amdgcn_global_load_lds(
        (const __attribute__((address_space(1))) unsigned int*)g,
        (__attribute__((address_space(3))) unsigned int*)l, 16, 0, 0);
}

// ---------------------------------------------------------------------------
// Weight transform: z[k=c*9+tap][co] -> zt5[s=cc*9+tap][gran4][co256][8ch]
__global__ void k_prep_zt(const float* __restrict__ z, bf16* __restrict__ zt5) {
    int s = blockIdx.x;                // 72 = cc*9 + tap, cc in 0..7 (32ch)
    int cc = s / 9, tap = s % 9;
    int co = threadIdx.x;
#pragma unroll
    for (int g = 0; g < 4; ++g) {
        bf16x8 pk;
#pragma unroll
        for (int e = 0; e < 8; ++e) {
            int c = cc * 32 + g * 8 + e;
            pk[e] = (bf16)z[(size_t)(c * 9 + tap) * 256 + co];
        }
        *(bf16x8*)(zt5 + ((size_t)(s * 4 + g) * 256 + co) * 8) = pk;
    }
}

// Column constants
__global__ void k_prep_cols(const float* __restrict__ z, const float* __restrict__ r,
                            float* __restrict__ zn, float* __restrict__ ch,
                            float* __restrict__ sh) {
    __shared__ float red[256];
    int co = blockIdx.x, t = threadIdx.x;
    float s = 0.f;
    for (int i = 0; i < 9; ++i) {
        float v = z[(size_t)(i * 256 + t) * 256 + co];
        s += v * v;
    }
    red[t] = s;
    __syncthreads();
    for (int off = 128; off >= 1; off >>= 1) {
        if (t < off) red[t] += red[t + off];
        __syncthreads();
    }
    if (t == 0) {
        zn[co] = fmaxf(sqrtf(red[0]), 1e-15f);
        float tc = 2.f * r[co];
        ch[co] = coshf(tc);
        sh[co] = sinhf(tc);
    }
}

// ---------------------------------------------------------------------------
// logmap0 * beta-ratio, transpose -> vt[B,HW,C] bf16, per-pixel sq (fp32).
__global__ void k_logmap(const float* __restrict__ x, unsigned int* __restrict__ vt_u,
                         float* __restrict__ sq, float Rbeta) {
    __shared__ float tile[256][33];
    __shared__ float red[8][32];
    __shared__ float afac[32];
    int tid = threadIdx.x;
    int blk = blockIdx.x;
    int b = blk >> 7;
    int pix0 = (blk & 127) << 5;

    for (int it = 0; it < 32; ++it) {
        int c = it * 8 + (tid >> 5);
        int p = tid & 31;
        tile[c][p] = x[((size_t)b * 256 + c) * 4096 + pix0 + p];
    }
    __syncthreads();

    {
        int part = tid >> 5, p = tid & 31;
        float s = 0.f;
        for (int i = 0; i < 32; ++i) {
            float v = tile[part * 32 + i][p];
            s += v * v;
        }
        red[part][p] = s;
    }
    __syncthreads();
    if (tid < 32) {
        float n2 = 0.f;
        for (int i = 0; i < 8; ++i) n2 += red[i][tid];
        float n = sqrtf(n2);
        float nc = fmaxf(n, 1e-15f);
        float a = atanhf(fminf(nc, 0.9999999f)) / nc * Rbeta;
        afac[tid] = a;
        sq[(size_t)b * 4096 + pix0 + tid] = a * a * n2;
    }
    __syncthreads();

    for (int it = 0; it < 16; ++it) {
        int idx = it * 256 + tid;
        int p = idx >> 7;
        int cp = idx & 127;
        float a = afac[p];
        float v0 = a * tile[2 * cp][p];
        float v1 = a * tile[2 * cp + 1][p];
        union { bf16 h[2]; unsigned int u; } pk;
        pk.h[0] = (bf16)v0;
        pk.h[1] = (bf16)v1;
        vt_u[((size_t)b * 4096 + pix0 + p) * 128 + cp] = pk.u;
    }
}

// ---------------------------------------------------------------------------
// Fused implicit-GEMM conv + hyperbolic FC epilogue.
// r11 (98us = 789 TF) sits at the m97 2-barrier ceiling: LDS-limited at
// 0.5 KB-read/MFMA. This round raises register reuse: wave tile 64px x 128co
// (acc[4][8] = 128 AGPR) -> 0.375 KB/MFMA and half the B-read redundancy.
// Block: 2 rows x 256 co, 4 waves (256 thr), 2 blocks/CU (LDS ~68 KB,
// waves_per_eu(2,2) -> 256-reg budget, r16-verified). Schedule = r11's
// proven one: B(s+1) each stage (4 loads), A restage at tap8 behind release
// barrier, uniform vmcnt(4), vmcnt(0) at s=71, 1 data barrier/stage,
// B triple-buffered with static tap%3 parity.
__global__ void
__attribute__((amdgpu_flat_work_group_size(256, 256)))
__attribute__((amdgpu_waves_per_eu(2, 2)))
k_hconv(const bf16* __restrict__ vt, const bf16* __restrict__ zt5,
        const float* __restrict__ sq,
        const float* __restrict__ znp, const float* __restrict__ chp,
        const float* __restrict__ shp, float* __restrict__ out) {
    __shared__ __align__(1024) char Asb[16896];      // 16 units x 1056 B
    __shared__ __align__(1024) char Bb3[3][16448];   // 4 gran x 4112 B each
    __shared__ float s_lds[128], lam_lds[128];
    __shared__ float red[128][2];

    int tid = threadIdx.x;
    int bid = blockIdx.x;
    int bh = ((bid & 7) << 6) | (bid >> 3);   // XCD-bijective: 512 = 8 x 64
    int b = bh >> 5, h0 = (bh & 31) << 1;

    // zero halo slots (0 and 65) of the 16 A units, once
    if (tid < 32) {
        int u = tid >> 1, side = tid & 1;
        *(f32x4*)(Asb + u * 1056 + side * 1040) = (f32x4){0.f, 0.f, 0.f, 0.f};
    }

    if (tid >= 128) {
        int t = tid - 128;
        int h = h0 + (t >> 6), w = t & 63;
        const float* sb = sq + ((size_t)b << 12);
        float q = 0.f;
#pragma unroll
        for (int dh = -1; dh <= 1; ++dh) {
            int hhh = h + dh;
            if ((unsigned)hhh >= 64u) continue;
#pragma unroll
            for (int dw = -1; dw <= 1; ++dw) {
                int ww = w + dw;
                if ((unsigned)ww >= 64u) continue;
                q += sb[hhh * 64 + ww];
            }
        }
        float ncl = fmaxf(sqrtf(q), 1e-15f);
        float p = __expf(2.f * ncl);
        float tt = (p - 1.f) / (p + 1.f);        // tanh(ncl)
        s_lds[t] = tt / ncl;                     // expmap scale
        lam_lds[t] = 2.f / (1.f - tt * tt);
    }

    int wave = tid >> 6, lane = tid & 63;
    int wn = wave & 1, wm = wave >> 1;    // wm row 0..1, wn co-half 0..1
    int lrow = lane & 15, lk = lane >> 4;

    f32x4 acc[4][8];
#pragma unroll
    for (int m = 0; m < 4; ++m)
#pragma unroll
        for (int n = 0; n < 8; ++n) acc[m][n] = (f32x4){0.f, 0.f, 0.f, 0.f};

    const bf16* vb = vt + (((size_t)b) << 12) * 256;

    // stage A chunk ccn: 16 units (r4 x g4); 4 gload_lds/thread
    auto stageA = [&](int ccn) {
#pragma unroll
        for (int it = 0; it < 4; ++it) {
            int u = wave * 4 + it;
            int r = u >> 2, g = u & 3;
            int hr = h0 - 1 + r;
            hr = hr < 0 ? 0 : (hr > 63 ? 63 : hr);   // clamped rows never read
            const bf16* gp = vb + ((size_t)(hr * 64 + lane)) * 256 + ccn * 32 + g * 8;
            gload16(gp, Asb + u * 1056 + 16);
        }
    };
    // stage B stage s into buffer dst: 16 KB linear; 4 gload_lds/thread
    auto stageB = [&](char* dst, int s) {
        const char* src = (const char*)zt5 + (size_t)s * 16384;
#pragma unroll
        for (int it = 0; it < 4; ++it) {
            gload16(src + it * 4096 + wave * 1024 + lane * 16,
                    dst + it * 4112 + wave * 1024);
        }
    };

    stageB((char*)Bb3[0], 0);
    stageA(0);
    __syncthreads();                      // drains prologue; s_lds visible
    SBAR();

    const char* ApB = Asb + lk * 1056 + lrow * 16;
    const int bOff = lk * 4112 + (wn * 128 + lrow) * 16;

#define STAGE(CCV, TAP)                                                      \
    {                                                                        \
        const int s_ = (CCV) * 9 + (TAP);                                    \
        if (s_ < 71) stageB((char*)Bb3[((TAP) + 1) % 3], s_ + 1);            \
        SBAR();                                                              \
        if (s_ < 71) { asm volatile("s_waitcnt vmcnt(4)" ::: "memory"); }    \
        else         { asm volatile("s_waitcnt vmcnt(0)" ::: "memory"); }    \
        SBAR();                                                              \
        asm volatile("s_barrier" ::: "memory");   /* stage data ready */     \
        SBAR();                                                              \
        {                                                                    \
            const int dh_ = (TAP) / 3 - 1, dw_ = (TAP) % 3 - 1;              \
            int hh_ = h0 + wm + dh_;                                         \
            if ((unsigned)hh_ < 64u) {                                       \
                const char* Ap_ = ApB + (wm + dh_ + 1) * 4224 + (dw_ + 1) * 16; \
                const char* Bp_ = (const char*)Bb3[(TAP) % 3] + bOff;        \
                bf16x8 a0 = *(const bf16x8*)(Ap_);                           \
                bf16x8 a1 = *(const bf16x8*)(Ap_ + 256);                     \
                bf16x8 a2 = *(const bf16x8*)(Ap_ + 512);                     \
                bf16x8 a3 = *(const bf16x8*)(Ap_ + 768);                     \
                __builtin_amdgcn_s_setprio(1);                               \
                _Pragma("unroll")                                            \
                for (int n = 0; n < 8; ++n) {                                \
                    bf16x8 bb = *(const bf16x8*)(Bp_ + n * 256);             \
                    acc[0][n] = __builtin_amdgcn_mfma_f32_16x16x32_bf16(a0, bb, acc[0][n], 0, 0, 0); \
                    acc[1][n] = __builtin_amdgcn_mfma_f32_16x16x32_bf16(a1, bb, acc[1][n], 0, 0, 0); \
                    acc[2][n] = __builtin_amdgcn_mfma_f32_16x16x32_bf16(a2, bb, acc[2][n], 0, 0, 0); \
                    acc[3][n] = __builtin_amdgcn_mfma_f32_16x16x32_bf16(a3, bb, acc[3][n], 0, 0, 0); \
                }                                                            \
                __builtin_amdgcn_s_setprio(0);                               \
            }                                                                \
        }                                                                    \
        if ((TAP) == 8 && (CCV) < 7) {                                       \
            SBAR();                                                          \
            asm volatile("s_barrier" ::: "memory");   /* WAR: A reads done */ \
            SBAR();                                                          \
            stageA((CCV) + 1);                                               \
            SBAR();                                                          \
        }                                                                    \
    }

#pragma unroll 1
    for (int cc = 0; cc < 8; ++cc) {
        STAGE(cc, 0) STAGE(cc, 1) STAGE(cc, 2)
        STAGE(cc, 3) STAGE(cc, 4) STAGE(cc, 5)
        STAGE(cc, 6) STAGE(cc, 7) STAGE(cc, 8)
    }
#undef STAGE

    // ---------------- epilogue (fast transcendental forms) ----------------
    float cz[8], sh8[8], tz[8];
#pragma unroll
    for (int n = 0; n < 8; ++n) {
        int co = wn * 128 + n * 16 + lrow;
        float zn = znp[co];
        cz[n] = chp[co] / zn;
        sh8[n] = shp[co];
        tz[n] = 2.f * zn;
    }

#pragma unroll
    for (int m = 0; m < 4; ++m) {
#pragma unroll
        for (int r = 0; r < 4; ++r) {
            int wp = wm * 64 + m * 16 + 4 * lk + r;   // block-local px slot
            float s = s_lds[wp], lam = lam_lds[wp];
            float lm1 = lam - 1.f;
            float psum = 0.f;
#pragma unroll
            for (int n = 0; n < 8; ++n) {
                float xz = s * acc[m][n][r];
                float inner = lam * xz * cz[n] - lm1 * sh8[n];
                float as = __logf(inner + sqrtf(inner * inner + 1.f)); // asinh
                float p = __expf(tz[n] * as);
                float w = 0.5f * (p - __builtin_amdgcn_rcpf(p));       // sinh
                acc[m][n][r] = w;
                psum += w * w;
            }
            psum += __shfl_xor(psum, 1);
            psum += __shfl_xor(psum, 2);
            psum += __shfl_xor(psum, 4);
            psum += __shfl_xor(psum, 8);
            if (lrow == 0) red[wp][wn] = psum;
        }
    }
    __syncthreads();

    float dinv[4][4];
#pragma unroll
    for (int m = 0; m < 4; ++m)
#pragma unroll
        for (int r = 0; r < 4; ++r) {
            int wp = wm * 64 + m * 16 + 4 * lk + r;
            float tot = red[wp][0] + red[wp][1];
            dinv[m][r] = __builtin_amdgcn_rcpf(1.f + sqrtf(1.f + tot));
        }

    float* ob = out + (size_t)b * 256 * 4096 + (h0 + wm) * 64;
#pragma unroll
    for (int m = 0; m < 4; ++m) {
#pragma unroll
        for (int n = 0; n < 8; ++n) {
            int co = wn * 128 + n * 16 + lrow;
            f32x4 o;
#pragma unroll
            for (int r = 0; r < 4; ++r) o[r] = acc[m][n][r] * dinv[m][r];
            *(f32x4*)(ob + (size_t)co * 4096 + m * 16 + 4 * lk) = o;
        }
    }
}

// ---------------------------------------------------------------------------
extern "C" void kernel_launch(void* const* d_in, const int* in_sizes, int n_in,
                              void* d_out, int out_size, void* d_ws, size_t ws_size,
                              hipStream_t stream) {
    const float* x = (const float*)d_in[0];   // [16,256,64,64]
    const float* z = (const float*)d_in[1];   // [2304,256]
    const float* r = (const float*)d_in[2];   // [256]
    float* out = (float*)d_out;               // [16,256,64,64]

    char* ws = (char*)d_ws;
    bf16* vt = (bf16*)ws;                         // 33,554,432 B (px-major)
    float* sq = (float*)(ws + 33554432);
    bf16* zt5 = (bf16*)(ws + 34078720);           // 72*16KB = 1,179,648 B
    float* zn = (float*)(ws + 35258368);
    float* ch = (float*)(ws + 35259392);
    float* sh = (float*)(ws + 35260416);
    if (ws_size < 35261440) return;

    double bni = lgamma(128.0) + lgamma(0.5) - lgamma(128.5);
    double bn = lgamma(1152.0) + lgamma(0.5) - lgamma(1152.5);
    float Rbeta = (float)exp(bn - bni);

    k_prep_zt<<<72, 256, 0, stream>>>(z, zt5);
    k_prep_cols<<<256, 256, 0, stream>>>(z, r, zn, ch, sh);
    k_logmap<<<2048, 256, 0, stream>>>(x, (unsigned int*)vt, sq, Rbeta);
    k_hconv<<<512, 256, 0, stream>>>(vt, zt5, sq, zn, ch, sh, out);
}

// Round 18
// 122.394 us; speedup vs baseline: 1.1587x; 1.0205x over previous
//
#include <hip/hip_runtime.h>
#include <cmath>

typedef __bf16 bf16;
typedef __bf16 bf16x8 __attribute__((ext_vector_type(8)));
typedef float f32x4 __attribute__((ext_vector_type(4)));

#define SBAR() __builtin_amdgcn_sched_barrier(0)

// B=16, C_IN=256, H=W=64, C_OUT=256, 3x3, stride 1, pad 1, CURV=1

__device__ inline void gload16(const void* g, void* l) {
    __builtin_amdgcn_global_load_lds(
        (const __attribute__((address_space(1))) unsigned int*)g,
        (__attribute__((address_space(3))) unsigned int*)l, 16, 0, 0);
}

// ---------------------------------------------------------------------------
// Weight transform: z[k=c*9+tap][co] -> zt5[s=cc*9+tap][gran4][co256][8ch]
__global__ void k_prep_zt(const float* __restrict__ z, bf16* __restrict__ zt5) {
    int s = blockIdx.x;                // 72 = cc*9 + tap, cc in 0..7 (32ch)
    int cc = s / 9, tap = s % 9;
    int co = threadIdx.x;
#pragma unroll
    for (int g = 0; g < 4; ++g) {
        bf16x8 pk;
#pragma unroll
        for (int e = 0; e < 8; ++e) {
            int c = cc * 32 + g * 8 + e;
            pk[e] = (bf16)z[(size_t)(c * 9 + tap) * 256 + co];
        }
        *(bf16x8*)(zt5 + ((size_t)(s * 4 + g) * 256 + co) * 8) = pk;
    }
}

// Column constants
__global__ void k_prep_cols(const float* __restrict__ z, const float* __restrict__ r,
                            float* __restrict__ zn, float* __restrict__ ch,
                            float* __restrict__ sh) {
    __shared__ float red[256];
    int co = blockIdx.x, t = threadIdx.x;
    float s = 0.f;
    for (int i = 0; i < 9; ++i) {
        float v = z[(size_t)(i * 256 + t) * 256 + co];
        s += v * v;
    }
    red[t] = s;
    __syncthreads();
    for (int off = 128; off >= 1; off >>= 1) {
        if (t < off) red[t] += red[t + off];
        __syncthreads();
    }
    if (t == 0) {
        zn[co] = fmaxf(sqrtf(red[0]), 1e-15f);
        float tc = 2.f * r[co];
        ch[co] = coshf(tc);
        sh[co] = sinhf(tc);
    }
}

// ---------------------------------------------------------------------------
// logmap0 * beta-ratio, transpose -> vt[B,HW,C] bf16, per-pixel sq (fp32).
__global__ void k_logmap(const float* __restrict__ x, unsigned int* __restrict__ vt_u,
                         float* __restrict__ sq, float Rbeta) {
    __shared__ float tile[256][33];
    __shared__ float red[8][32];
    __shared__ float afac[32];
    int tid = threadIdx.x;
    int blk = blockIdx.x;
    int b = blk >> 7;
    int pix0 = (blk & 127) << 5;

    for (int it = 0; it < 32; ++it) {
        int c = it * 8 + (tid >> 5);
        int p = tid & 31;
        tile[c][p] = x[((size_t)b * 256 + c) * 4096 + pix0 + p];
    }
    __syncthreads();

    {
        int part = tid >> 5, p = tid & 31;
        float s = 0.f;
        for (int i = 0; i < 32; ++i) {
            float v = tile[part * 32 + i][p];
            s += v * v;
        }
        red[part][p] = s;
    }
    __syncthreads();
    if (tid < 32) {
        float n2 = 0.f;
        for (int i = 0; i < 8; ++i) n2 += red[i][tid];
        float n = sqrtf(n2);
        float nc = fmaxf(n, 1e-15f);
        float a = atanhf(fminf(nc, 0.9999999f)) / nc * Rbeta;
        afac[tid] = a;
        sq[(size_t)b * 4096 + pix0 + tid] = a * a * n2;
    }
    __syncthreads();

    for (int it = 0; it < 16; ++it) {
        int idx = it * 256 + tid;
        int p = idx >> 7;
        int cp = idx & 127;
        float a = afac[p];
        float v0 = a * tile[2 * cp][p];
        float v1 = a * tile[2 * cp + 1][p];
        union { bf16 h[2]; unsigned int u; } pk;
        pk.h[0] = (bf16)v0;
        pk.h[1] = (bf16)v1;
        vt_u[((size_t)b * 4096 + pix0 + p) * 128 + cp] = pk.u;
    }
}

// ---------------------------------------------------------------------------
// Fused implicit-GEMM conv + hyperbolic FC epilogue.
// r17 geometry (2 rows x 256co, 4 waves, acc[4][8], 2 blocks/CU, fused
// boxsum) + INTRA-WAVE B-frag prefetch: B-frags(s+1) ds_read at stage s
// (ping-pong regs, unconditional), MFMA(s) consumes frags read a stage
// earlier; B global issue distance 2 (buffer (s+2)%3, WAR-safe across the
// per-stage barrier). Uniform vmcnt(4); vmcnt(0) at s>=70. A single-buffer
// with tap8 release-barrier restage (r11/r17 proven protocol).
__global__ void
__attribute__((amdgpu_flat_work_group_size(256, 256)))
__attribute__((amdgpu_waves_per_eu(2, 2)))
k_hconv(const bf16* __restrict__ vt, const bf16* __restrict__ zt5,
        const float* __restrict__ sq,
        const float* __restrict__ znp, const float* __restrict__ chp,
        const float* __restrict__ shp, float* __restrict__ out) {
    __shared__ __align__(1024) char Asb[16896];      // 16 units x 1056 B
    __shared__ __align__(1024) char Bb3[3][16448];   // 4 gran x 4112 B each
    __shared__ float s_lds[128], lam_lds[128];
    __shared__ float red[128][2];

    int tid = threadIdx.x;
    int bid = blockIdx.x;
    int bh = ((bid & 7) << 6) | (bid >> 3);   // XCD-bijective: 512 = 8 x 64
    int b = bh >> 5, h0 = (bh & 31) << 1;

    // zero halo slots (0 and 65) of the 16 A units, once
    if (tid < 32) {
        int u = tid >> 1, side = tid & 1;
        *(f32x4*)(Asb + u * 1056 + side * 1040) = (f32x4){0.f, 0.f, 0.f, 0.f};
    }

    if (tid >= 128) {
        int t = tid - 128;
        int h = h0 + (t >> 6), w = t & 63;
        const float* sb = sq + ((size_t)b << 12);
        float q = 0.f;
#pragma unroll
        for (int dh = -1; dh <= 1; ++dh) {
            int hhh = h + dh;
            if ((unsigned)hhh >= 64u) continue;
#pragma unroll
            for (int dw = -1; dw <= 1; ++dw) {
                int ww = w + dw;
                if ((unsigned)ww >= 64u) continue;
                q += sb[hhh * 64 + ww];
            }
        }
        float ncl = fmaxf(sqrtf(q), 1e-15f);
        float p = __expf(2.f * ncl);
        float tt = (p - 1.f) / (p + 1.f);        // tanh(ncl)
        s_lds[t] = tt / ncl;                     // expmap scale
        lam_lds[t] = 2.f / (1.f - tt * tt);
    }

    int wave = tid >> 6, lane = tid & 63;
    int wn = wave & 1, wm = wave >> 1;    // wm row 0..1, wn co-half 0..1
    int lrow = lane & 15, lk = lane >> 4;

    f32x4 acc[4][8];
#pragma unroll
    for (int m = 0; m < 4; ++m)
#pragma unroll
        for (int n = 0; n < 8; ++n) acc[m][n] = (f32x4){0.f, 0.f, 0.f, 0.f};

    const bf16* vb = vt + (((size_t)b) << 12) * 256;

    // stage A chunk ccn: 16 units (r4 x g4); 4 gload_lds/thread
    auto stageA = [&](int ccn) {
#pragma unroll
        for (int it = 0; it < 4; ++it) {
            int u = wave * 4 + it;
            int r = u >> 2, g = u & 3;
            int hr = h0 - 1 + r;
            hr = hr < 0 ? 0 : (hr > 63 ? 63 : hr);   // clamped rows never read
            const bf16* gp = vb + ((size_t)(hr * 64 + lane)) * 256 + ccn * 32 + g * 8;
            gload16(gp, Asb + u * 1056 + 16);
        }
    };
    // stage B stage s into buffer dst: 16 KB linear; 4 gload_lds/thread
    auto stageB = [&](char* dst, int s) {
        const char* src = (const char*)zt5 + (size_t)s * 16384;
#pragma unroll
        for (int it = 0; it < 4; ++it) {
            gload16(src + it * 4096 + wave * 1024 + lane * 16,
                    dst + it * 4112 + wave * 1024);
        }
    };

    stageB((char*)Bb3[0], 0);
    stageB((char*)Bb3[1], 1);
    stageA(0);
    __syncthreads();                      // drains prologue; s_lds visible
    SBAR();

    const char* ApB = Asb + lk * 1056 + lrow * 16;
    const int bOff = lk * 4112 + (wn * 128 + lrow) * 16;

    bf16x8 bfA[8], bfB[8];
#pragma unroll
    for (int n = 0; n < 8; ++n)           // frags for s=0 from buf0
        bfA[n] = *(const bf16x8*)((const char*)Bb3[0] + bOff + n * 256);

#define STAGE(CCV, TAP, CUR, NXT)                                            \
    {                                                                        \
        const int s_ = (CCV) * 9 + (TAP);                                    \
        if (s_ + 2 < 72) stageB((char*)Bb3[((TAP) + 2) % 3], s_ + 2);        \
        SBAR();                                                              \
        if (s_ < 70) { asm volatile("s_waitcnt vmcnt(4)" ::: "memory"); }    \
        else         { asm volatile("s_waitcnt vmcnt(0)" ::: "memory"); }    \
        SBAR();                                                              \
        asm volatile("s_barrier" ::: "memory");   /* B(s+1)/A data ready */  \
        SBAR();                                                              \
        if (s_ + 1 < 72) {   /* unconditional B-frag prefetch for s+1 */     \
            const char* Bn_ = (const char*)Bb3[((TAP) + 1) % 3] + bOff;      \
            NXT[0] = *(const bf16x8*)(Bn_);                                  \
            NXT[1] = *(const bf16x8*)(Bn_ + 256);                            \
            NXT[2] = *(const bf16x8*)(Bn_ + 512);                            \
            NXT[3] = *(const bf16x8*)(Bn_ + 768);                            \
            NXT[4] = *(const bf16x8*)(Bn_ + 1024);                           \
            NXT[5] = *(const bf16x8*)(Bn_ + 1280);                           \
            NXT[6] = *(const bf16x8*)(Bn_ + 1536);                           \
            NXT[7] = *(const bf16x8*)(Bn_ + 1792);                           \
        }                                                                    \
        {                                                                    \
            const int dh_ = (TAP) / 3 - 1, dw_ = (TAP) % 3 - 1;              \
            int hh_ = h0 + wm + dh_;                                         \
            if ((unsigned)hh_ < 64u) {                                       \
                const char* Ap_ = ApB + (wm + dh_ + 1) * 4224 + (dw_ + 1) * 16; \
                bf16x8 a0 = *(const bf16x8*)(Ap_);                           \
                bf16x8 a1 = *(const bf16x8*)(Ap_ + 256);                     \
                bf16x8 a2 = *(const bf16x8*)(Ap_ + 512);                     \
                bf16x8 a3 = *(const bf16x8*)(Ap_ + 768);                     \
                __builtin_amdgcn_s_setprio(1);                               \
                _Pragma("unroll")                                            \
                for (int n = 0; n < 8; ++n) {                                \
                    acc[0][n] = __builtin_amdgcn_mfma_f32_16x16x32_bf16(a0, CUR[n], acc[0][n], 0, 0, 0); \
                    acc[1][n] = __builtin_amdgcn_mfma_f32_16x16x32_bf16(a1, CUR[n], acc[1][n], 0, 0, 0); \
                    acc[2][n] = __builtin_amdgcn_mfma_f32_16x16x32_bf16(a2, CUR[n], acc[2][n], 0, 0, 0); \
                    acc[3][n] = __builtin_amdgcn_mfma_f32_16x16x32_bf16(a3, CUR[n], acc[3][n], 0, 0, 0); \
                }                                                            \
                __builtin_amdgcn_s_setprio(0);                               \
            }                                                                \
        }                                                                    \
        if ((TAP) == 8 && (CCV) < 7) {                                       \
            SBAR();                                                          \
            asm volatile("s_barrier" ::: "memory");   /* WAR: A reads done */ \
            SBAR();                                                          \
            stageA((CCV) + 1);                                               \
            SBAR();                                                          \
        }                                                                    \
    }

#pragma unroll 1
    for (int cc2 = 0; cc2 < 4; ++cc2) {
        const int c0 = 2 * cc2, c1 = c0 + 1;
        STAGE(c0, 0, bfA, bfB) STAGE(c0, 1, bfB, bfA) STAGE(c0, 2, bfA, bfB)
        STAGE(c0, 3, bfB, bfA) STAGE(c0, 4, bfA, bfB) STAGE(c0, 5, bfB, bfA)
        STAGE(c0, 6, bfA, bfB) STAGE(c0, 7, bfB, bfA) STAGE(c0, 8, bfA, bfB)
        STAGE(c1, 0, bfB, bfA) STAGE(c1, 1, bfA, bfB) STAGE(c1, 2, bfB, bfA)
        STAGE(c1, 3, bfA, bfB) STAGE(c1, 4, bfB, bfA) STAGE(c1, 5, bfA, bfB)
        STAGE(c1, 6, bfB, bfA) STAGE(c1, 7, bfA, bfB) STAGE(c1, 8, bfB, bfA)
    }
#undef STAGE

    // ---------------- epilogue (fast transcendental forms) ----------------
    float cz[8], sh8[8], tz[8];
#pragma unroll
    for (int n = 0; n < 8; ++n) {
        int co = wn * 128 + n * 16 + lrow;
        float zn = znp[co];
        cz[n] = chp[co] / zn;
        sh8[n] = shp[co];
        tz[n] = 2.f * zn;
    }

#pragma unroll
    for (int m = 0; m < 4; ++m) {
#pragma unroll
        for (int r = 0; r < 4; ++r) {
            int wp = wm * 64 + m * 16 + 4 * lk + r;   // block-local px slot
            float s = s_lds[wp], lam = lam_lds[wp];
            float lm1 = lam - 1.f;
            float psum = 0.f;
#pragma unroll
            for (int n = 0; n < 8; ++n) {
                float xz = s * acc[m][n][r];
                float inner = lam * xz * cz[n] - lm1 * sh8[n];
                float as = __logf(inner + sqrtf(inner * inner + 1.f)); // asinh
                float p = __expf(tz[n] * as);
                float w = 0.5f * (p - __builtin_amdgcn_rcpf(p));       // sinh
                acc[m][n][r] = w;
                psum += w * w;
            }
            psum += __shfl_xor(psum, 1);
            psum += __shfl_xor(psum, 2);
            psum += __shfl_xor(psum, 4);
            psum += __shfl_xor(psum, 8);
            if (lrow == 0) red[wp][wn] = psum;
        }
    }
    __syncthreads();

    float dinv[4][4];
#pragma unroll
    for (int m = 0; m < 4; ++m)
#pragma unroll
        for (int r = 0; r < 4; ++r) {
            int wp = wm * 64 + m * 16 + 4 * lk + r;
            float tot = red[wp][0] + red[wp][1];
            dinv[m][r] = __builtin_amdgcn_rcpf(1.f + sqrtf(1.f + tot));
        }

    float* ob = out + (size_t)b * 256 * 4096 + (h0 + wm) * 64;
#pragma unroll
    for (int m = 0; m < 4; ++m) {
#pragma unroll
        for (int n = 0; n < 8; ++n) {
            int co = wn * 128 + n * 16 + lrow;
            f32x4 o;
#pragma unroll
            for (int r = 0; r < 4; ++r) o[r] = acc[m][n][r] * dinv[m][r];
            *(f32x4*)(ob + (size_t)co * 4096 + m * 16 + 4 * lk) = o;
        }
    }
}

// ---------------------------------------------------------------------------
extern "C" void kernel_launch(void* const* d_in, const int* in_sizes, int n_in,
                              void* d_out, int out_size, void* d_ws, size_t ws_size,
                              hipStream_t stream) {
    const float* x = (const float*)d_in[0];   // [16,256,64,64]
    const float* z = (const float*)d_in[1];   // [2304,256]
    const float* r = (const float*)d_in[2];   // [256]
    float* out = (float*)d_out;               // [16,256,64,64]

    char* ws = (char*)d_ws;
    bf16* vt = (bf16*)ws;                         // 33,554,432 B (px-major)
    float* sq = (float*)(ws + 33554432);
    bf16* zt5 = (bf16*)(ws + 34078720);           // 72*16KB = 1,179,648 B
    float* zn = (float*)(ws + 35258368);
    float* ch = (float*)(ws + 35259392);
    float* sh = (float*)(ws + 35260416);
    if (ws_size < 35261440) return;

    double bni = lgamma(128.0) + lgamma(0.5) - lgamma(128.5);
    double bn = lgamma(1152.0) + lgamma(0.5) - lgamma(1152.5);
    float Rbeta = (float)exp(bn - bni);

    k_prep_zt<<<72, 256, 0, stream>>>(z, zt5);
    k_prep_cols<<<256, 256, 0, stream>>>(z, r, zn, ch, sh);
    k_logmap<<<2048, 256, 0, stream>>>(x, (unsigned int*)vt, sq, Rbeta);
    k_hconv<<<512, 256, 0, stream>>>(vt, zt5, sq, zn, ch, sh, out);
}

// Round 19
// 120.557 us; speedup vs baseline: 1.1764x; 1.0152x over previous
//
#include <hip/hip_runtime.h>
#include <cmath>

typedef __bf16 bf16;
typedef __bf16 bf16x8 __attribute__((ext_vector_type(8)));
typedef float f32x4 __attribute__((ext_vector_type(4)));

#define SBAR() __builtin_amdgcn_sched_barrier(0)

// B=16, C_IN=256, H=W=64, C_OUT=256, 3x3, stride 1, pad 1, CURV=1

__device__ inline void gload16(const void* g, void* l) {
    __builtin_amdgcn_global_load_lds(
        (const __attribute__((address_space(1))) unsigned int*)g,
        (__attribute__((address_space(3))) unsigned int*)l, 16, 0, 0);
}

// ---------------------------------------------------------------------------
// Fused weight prep: blocks 0..71 build zt5[s][gran4][co256][8ch] bf16;
// blocks 72..327 compute column constants zn/ch/sh (one co per block).
__global__ void k_prep(const float* __restrict__ z, const float* __restrict__ r,
                       bf16* __restrict__ zt5, float* __restrict__ zn,
                       float* __restrict__ ch, float* __restrict__ sh) {
    int blk = blockIdx.x;
    if (blk < 72) {
        int cc = blk / 9, tap = blk % 9;
        int co = threadIdx.x;
#pragma unroll
        for (int g = 0; g < 4; ++g) {
            bf16x8 pk;
#pragma unroll
            for (int e = 0; e < 8; ++e) {
                int c = cc * 32 + g * 8 + e;
                pk[e] = (bf16)z[(size_t)(c * 9 + tap) * 256 + co];
            }
            *(bf16x8*)(zt5 + ((size_t)(blk * 4 + g) * 256 + co) * 8) = pk;
        }
    } else {
        __shared__ float red[256];
        int co = blk - 72, t = threadIdx.x;
        float s = 0.f;
        for (int i = 0; i < 9; ++i) {
            float v = z[(size_t)(i * 256 + t) * 256 + co];
            s += v * v;
        }
        red[t] = s;
        __syncthreads();
        for (int off = 128; off >= 1; off >>= 1) {
            if (t < off) red[t] += red[t + off];
            __syncthreads();
        }
        if (t == 0) {
            zn[co] = fmaxf(sqrtf(red[0]), 1e-15f);
            float tc = 2.f * r[co];
            ch[co] = coshf(tc);
            sh[co] = sinhf(tc);
        }
    }
}

// ---------------------------------------------------------------------------
// logmap0 * beta-ratio, transpose -> vt[B,HW,C] bf16, per-pixel sq (fp32).
// Phase 1 vectorized to float4 (G13).
__global__ void k_logmap(const float* __restrict__ x, unsigned int* __restrict__ vt_u,
                         float* __restrict__ sq, float Rbeta) {
    __shared__ float tile[256][33];
    __shared__ float red[8][32];
    __shared__ float afac[32];
    int tid = threadIdx.x;
    int blk = blockIdx.x;
    int b = blk >> 7;
    int pix0 = (blk & 127) << 5;

    for (int it = 0; it < 8; ++it) {
        int c = it * 32 + (tid >> 3);
        int p4 = (tid & 7) * 4;
        f32x4 v = *(const f32x4*)(x + ((size_t)b * 256 + c) * 4096 + pix0 + p4);
        tile[c][p4] = v[0];
        tile[c][p4 + 1] = v[1];
        tile[c][p4 + 2] = v[2];
        tile[c][p4 + 3] = v[3];
    }
    __syncthreads();

    {
        int part = tid >> 5, p = tid & 31;
        float s = 0.f;
        for (int i = 0; i < 32; ++i) {
            float v = tile[part * 32 + i][p];
            s += v * v;
        }
        red[part][p] = s;
    }
    __syncthreads();
    if (tid < 32) {
        float n2 = 0.f;
        for (int i = 0; i < 8; ++i) n2 += red[i][tid];
        float n = sqrtf(n2);
        float nc = fmaxf(n, 1e-15f);
        float a = atanhf(fminf(nc, 0.9999999f)) / nc * Rbeta;
        afac[tid] = a;
        sq[(size_t)b * 4096 + pix0 + tid] = a * a * n2;
    }
    __syncthreads();

    for (int it = 0; it < 16; ++it) {
        int idx = it * 256 + tid;
        int p = idx >> 7;
        int cp = idx & 127;
        float a = afac[p];
        float v0 = a * tile[2 * cp][p];
        float v1 = a * tile[2 * cp + 1][p];
        union { bf16 h[2]; unsigned int u; } pk;
        pk.h[0] = (bf16)v0;
        pk.h[1] = (bf16)v1;
        vt_u[((size_t)b * 4096 + pix0 + p) * 128 + cp] = pk.u;
    }
}

// ---------------------------------------------------------------------------
// Fused implicit-GEMM conv + hyperbolic FC epilogue — r11 structure verbatim
// (best measured: 98.1 us) with the 3x3 box-sum of sq fused in (r16-proven),
// removing the separate k_boxsum launch.
//   Block: 2 rows (128 px) x 256 co, 8 waves. Wave: 64 px x 64 co
//   (acc[4][4]; 128 unified regs/wave -> 16 waves/CU = reg ceiling).
//   A single-buffered [4r][4g][66-halo] (restage at tap8 behind release
//   barrier); B TRIPLE-buffered (read tap%3, write (tap+1)%3, static since
//   9%3==0; no trailing barrier). Uniform vmcnt(2), vmcnt(0) at s=71.
__global__ void
__attribute__((amdgpu_flat_work_group_size(512, 512)))
__attribute__((amdgpu_waves_per_eu(4, 4)))
k_hconv(const bf16* __restrict__ vt, const bf16* __restrict__ zt5,
        const float* __restrict__ sq,
        const float* __restrict__ znp, const float* __restrict__ chp,
        const float* __restrict__ shp, float* __restrict__ out) {
    __shared__ __align__(1024) char Asb[16896];      // 16 units x 1056 B
    __shared__ __align__(1024) char Bsb[3][16448];   // 3 bufs x 4 gran x 4112 B
    __shared__ float s_lds[128], lam_lds[128];
    __shared__ float red[128][4];

    int tid = threadIdx.x;
    int bid = blockIdx.x;
    int bh = ((bid & 7) << 6) | (bid >> 3);   // XCD-bijective: 512 = 8 x 64
    int b = bh >> 5, h0 = (bh & 31) << 1;

    // zero halo slots (0 and 65) of the 16 A units, once
    if (tid < 32) {
        int u = tid >> 1, side = tid & 1;
        *(f32x4*)(Asb + u * 1056 + side * 1040) = (f32x4){0.f, 0.f, 0.f, 0.f};
    }

    if (tid >= 128 && tid < 256) {
        int t = tid - 128;
        int h = h0 + (t >> 6), w = t & 63;
        const float* sb = sq + ((size_t)b << 12);
        float q = 0.f;
#pragma unroll
        for (int dh = -1; dh <= 1; ++dh) {
            int hhh = h + dh;
            if ((unsigned)hhh >= 64u) continue;
#pragma unroll
            for (int dw = -1; dw <= 1; ++dw) {
                int ww = w + dw;
                if ((unsigned)ww >= 64u) continue;
                q += sb[hhh * 64 + ww];
            }
        }
        float ncl = fmaxf(sqrtf(q), 1e-15f);
        float p = __expf(2.f * ncl);
        float tt = (p - 1.f) / (p + 1.f);        // tanh(ncl)
        s_lds[t] = tt / ncl;                     // expmap scale
        lam_lds[t] = 2.f / (1.f - tt * tt);
    }

    int wave = tid >> 6, lane = tid & 63;
    int wn = wave & 3, wm = wave >> 2;    // wm row 0..1, wn co-quarter 0..3
    int lrow = lane & 15, lk = lane >> 4;

    f32x4 acc[4][4];
#pragma unroll
    for (int m = 0; m < 4; ++m)
#pragma unroll
        for (int n = 0; n < 4; ++n) acc[m][n] = (f32x4){0.f, 0.f, 0.f, 0.f};

    const bf16* vb = vt + (((size_t)b) << 12) * 256;

    // stage A chunk ccn: 16 units (r4 x g4); 2 loads/wave
    auto stageA = [&](int ccn) {
#pragma unroll
        for (int it = 0; it < 2; ++it) {
            int u = wave * 2 + it;
            int r = u >> 2, g = u & 3;
            int hr = h0 - 1 + r;
            hr = hr < 0 ? 0 : (hr > 63 ? 63 : hr);   // clamped rows never read
            const bf16* gp = vb + ((size_t)(hr * 64 + lane)) * 256 + ccn * 32 + g * 8;
            gload16(gp, Asb + u * 1056 + 16);
        }
    };
    // stage B stage snext into buffer dst: linear 16 KB copy; 2 loads/wave
    auto stageB = [&](char* dst, int snext) {
        const char* src = (const char*)zt5 + (size_t)snext * 16384;
#pragma unroll
        for (int it = 0; it < 2; ++it) {
            int u = wave * 2 + it;
            gload16(src + u * 1024 + lane * 16,
                    dst + (u >> 2) * 4112 + (u & 3) * 1024);
        }
    };

    stageB((char*)Bsb[0], 0);
    stageA(0);
    __syncthreads();                      // drains prologue; s_lds visible
    SBAR();

    // per-lane invariant LDS read bases
    const char* ApB = Asb + lk * 1056 + lrow * 16;
    const int bOff = lk * 4112 + wn * 1024 + lrow * 16;

#pragma unroll 1
    for (int cc = 0; cc < 8; ++cc) {
        const int sbase = cc * 9;
        const bool notlast = (cc < 7);

#pragma unroll
        for (int tap = 0; tap < 9; ++tap) {
            const int s = sbase + tap;
            if (s < 71) stageB((char*)Bsb[(tap + 1) % 3], s + 1);
            SBAR();
            if (s < 71) { asm volatile("s_waitcnt vmcnt(2)" ::: "memory"); }
            else        { asm volatile("s_waitcnt vmcnt(0)" ::: "memory"); }
            SBAR();
            asm volatile("s_barrier" ::: "memory");   // stage-s data ready
            SBAR();

            const int dh = tap / 3 - 1, dw = tap % 3 - 1;
            int hh = h0 + wm + dh;
            if ((unsigned)hh < 64u) {                 // wave-uniform skip
                const char* Ap = ApB + (wm + dh + 1) * 4224 + (dw + 1) * 16;
                const char* Bp = (const char*)Bsb[tap % 3] + bOff;
                bf16x8 a0 = *(const bf16x8*)(Ap);
                bf16x8 a1 = *(const bf16x8*)(Ap + 256);
                bf16x8 a2 = *(const bf16x8*)(Ap + 512);
                bf16x8 a3 = *(const bf16x8*)(Ap + 768);
                bf16x8 b0 = *(const bf16x8*)(Bp);
                bf16x8 b1 = *(const bf16x8*)(Bp + 256);
                bf16x8 b2 = *(const bf16x8*)(Bp + 512);
                bf16x8 b3 = *(const bf16x8*)(Bp + 768);
                __builtin_amdgcn_s_setprio(1);
                acc[0][0] = __builtin_amdgcn_mfma_f32_16x16x32_bf16(a0, b0, acc[0][0], 0, 0, 0);
                acc[1][0] = __builtin_amdgcn_mfma_f32_16x16x32_bf16(a1, b0, acc[1][0], 0, 0, 0);
                acc[2][0] = __builtin_amdgcn_mfma_f32_16x16x32_bf16(a2, b0, acc[2][0], 0, 0, 0);
                acc[3][0] = __builtin_amdgcn_mfma_f32_16x16x32_bf16(a3, b0, acc[3][0], 0, 0, 0);
                acc[0][1] = __builtin_amdgcn_mfma_f32_16x16x32_bf16(a0, b1, acc[0][1], 0, 0, 0);
                acc[1][1] = __builtin_amdgcn_mfma_f32_16x16x32_bf16(a1, b1, acc[1][1], 0, 0, 0);
                acc[2][1] = __builtin_amdgcn_mfma_f32_16x16x32_bf16(a2, b1, acc[2][1], 0, 0, 0);
                acc[3][1] = __builtin_amdgcn_mfma_f32_16x16x32_bf16(a3, b1, acc[3][1], 0, 0, 0);
                acc[0][2] = __builtin_amdgcn_mfma_f32_16x16x32_bf16(a0, b2, acc[0][2], 0, 0, 0);
                acc[1][2] = __builtin_amdgcn_mfma_f32_16x16x32_bf16(a1, b2, acc[1][2], 0, 0, 0);
                acc[2][2] = __builtin_amdgcn_mfma_f32_16x16x32_bf16(a2, b2, acc[2][2], 0, 0, 0);
                acc[3][2] = __builtin_amdgcn_mfma_f32_16x16x32_bf16(a3, b2, acc[3][2], 0, 0, 0);
                acc[0][3] = __builtin_amdgcn_mfma_f32_16x16x32_bf16(a0, b3, acc[0][3], 0, 0, 0);
                acc[1][3] = __builtin_amdgcn_mfma_f32_16x16x32_bf16(a1, b3, acc[1][3], 0, 0, 0);
                acc[2][3] = __builtin_amdgcn_mfma_f32_16x16x32_bf16(a2, b3, acc[2][3], 0, 0, 0);
                acc[3][3] = __builtin_amdgcn_mfma_f32_16x16x32_bf16(a3, b3, acc[3][3], 0, 0, 0);
                __builtin_amdgcn_s_setprio(0);
            }
            SBAR();
            if (tap == 8) {
                // cc tail: all A[cc] reads done -> safe to restage A in place
                asm volatile("s_barrier" ::: "memory");
                SBAR();
                if (notlast) stageA(cc + 1);
                SBAR();
            }
        }
    }

    // ---------------- epilogue (fast transcendental forms) ----------------
    float cz[4], sh4[4], tz[4];
#pragma unroll
    for (int n = 0; n < 4; ++n) {
        int co = wn * 64 + n * 16 + lrow;
        float zn = znp[co];
        cz[n] = chp[co] / zn;
        sh4[n] = shp[co];
        tz[n] = 2.f * zn;
    }

#pragma unroll
    for (int m = 0; m < 4; ++m) {
#pragma unroll
        for (int r = 0; r < 4; ++r) {
            int wp = wm * 64 + m * 16 + 4 * lk + r;   // block-local px slot
            float s = s_lds[wp], lam = lam_lds[wp];
            float lm1 = lam - 1.f;
            float psum = 0.f;
#pragma unroll
            for (int n = 0; n < 4; ++n) {
                float xz = s * acc[m][n][r];
                float inner = lam * xz * cz[n] - lm1 * sh4[n];
                float as = __logf(inner + sqrtf(inner * inner + 1.f)); // asinh
                float p = __expf(tz[n] * as);
                float w = 0.5f * (p - __builtin_amdgcn_rcpf(p));       // sinh
                acc[m][n][r] = w;
                psum += w * w;
            }
            psum += __shfl_xor(psum, 1);
            psum += __shfl_xor(psum, 2);
            psum += __shfl_xor(psum, 4);
            psum += __shfl_xor(psum, 8);
            if (lrow == 0) red[wp][wn] = psum;
        }
    }
    __syncthreads();

    float dinv[4][4];
#pragma unroll
    for (int m = 0; m < 4; ++m)
#pragma unroll
        for (int r = 0; r < 4; ++r) {
            int wp = wm * 64 + m * 16 + 4 * lk + r;
            float tot = (red[wp][0] + red[wp][1]) + (red[wp][2] + red[wp][3]);
            dinv[m][r] = __builtin_amdgcn_rcpf(1.f + sqrtf(1.f + tot));
        }

    float* ob = out + (size_t)b * 256 * 4096 + (h0 + wm) * 64;
#pragma unroll
    for (int m = 0; m < 4; ++m) {
#pragma unroll
        for (int n = 0; n < 4; ++n) {
            int co = wn * 64 + n * 16 + lrow;
            f32x4 o;
#pragma unroll
            for (int r = 0; r < 4; ++r) o[r] = acc[m][n][r] * dinv[m][r];
            *(f32x4*)(ob + (size_t)co * 4096 + m * 16 + 4 * lk) = o;
        }
    }
}

// ---------------------------------------------------------------------------
extern "C" void kernel_launch(void* const* d_in, const int* in_sizes, int n_in,
                              void* d_out, int out_size, void* d_ws, size_t ws_size,
                              hipStream_t stream) {
    const float* x = (const float*)d_in[0];   // [16,256,64,64]
    const float* z = (const float*)d_in[1];   // [2304,256]
    const float* r = (const float*)d_in[2];   // [256]
    float* out = (float*)d_out;               // [16,256,64,64]

    char* ws = (char*)d_ws;
    bf16* vt = (bf16*)ws;                         // 33,554,432 B (px-major)
    float* sq = (float*)(ws + 33554432);
    bf16* zt5 = (bf16*)(ws + 34078720);           // 72*16KB = 1,179,648 B
    float* zn = (float*)(ws + 35258368);
    float* ch = (float*)(ws + 35259392);
    float* sh = (float*)(ws + 35260416);
    if (ws_size < 35261440) return;

    double bni = lgamma(128.0) + lgamma(0.5) - lgamma(128.5);
    double bn = lgamma(1152.0) + lgamma(0.5) - lgamma(1152.5);
    float Rbeta = (float)exp(bn - bni);

    k_prep<<<328, 256, 0, stream>>>(z, r, zt5, zn, ch, sh);
    k_logmap<<<2048, 256, 0, stream>>>(x, (unsigned int*)vt, sq, Rbeta);
    k_hconv<<<512, 512, 0, stream>>>(vt, zt5, sq, zn, ch, sh, out);
}